// Round 8
// baseline (549.829 us; speedup 1.0000x reference)
//
#include <hip/hip_runtime.h>

namespace {

constexpr int Bsz = 16, Nsz = 2048, Esz = 1024, Gsz = 2, Vsz = 320, Dsz = 512;
constexpr int Msz = Bsz * Nsz;   // 32768 rows
constexpr int Fsz = Gsz * Vsz;   // 640
constexpr int BM = 128, BN = 128, BK = 32;
constexpr int NKC = Esz / 32;    // 32 k-chunks
constexpr int NMB = Msz / 16;    // 2048 m-blobs
constexpr int NFB = Fsz / 16;    // 40 f-blobs

typedef __attribute__((ext_vector_type(8))) short bf16x8;
typedef __attribute__((ext_vector_type(4))) float f32x4;
typedef unsigned int u32;
typedef unsigned short u16;

__device__ __forceinline__ void load_lds16(const void* g, void* l) {
  __builtin_amdgcn_global_load_lds(
      (const __attribute__((address_space(1))) u32*)g,
      (__attribute__((address_space(3))) u32*)l, 16, 0, 0);
}

__device__ __forceinline__ ushort f2bf(float f) {
  union { float f; unsigned u; } v; v.f = f;
  unsigned r = (v.u + 0x7FFFu + ((v.u >> 16) & 1u)) >> 16;  // RNE
  return (ushort)r;
}
__device__ __forceinline__ float bf2f(ushort h) {
  union { unsigned u; float f; } v; v.u = ((unsigned)h) << 16;
  return v.f;
}

// precise gumbel (matches earlier rounds which scored absmax 0)
__device__ __forceinline__ float gumb_precise(float uu) {
  const float C0 = 1.0f - 2.0f * 1e-7f;
  float up = uu * C0;
  up = up + 1e-7f;
  return -logf(-logf(up));
}
// fast gumbel for candidate SELECTION only (abs err <~2e-5, threshold 1e-3)
__device__ __forceinline__ float gumb_fast(float uu) {
  const float C0 = 1.0f - 2.0f * 1e-7f;
  const float up = fmaf(uu, C0, 1e-7f);
  const float d = 1.0f - up;  // exact for up>=0.5 (Sterbenz)
  const float ypoly =
      d * fmaf(d, fmaf(d, fmaf(d, fmaf(d, 0.2f, 0.25f), 0.33333334f), 0.5f), 1.0f);
  const float yfast = -__logf(up);
  const float y = (up >= 0.84f) ? ypoly : yfast;
  return -__logf(y);
}

struct Top2 { float v1, v2; int i1, i2; };
__device__ __forceinline__ void t2_feed(Top2& t, float z, int f) {
  if (z > t.v1 || (z == t.v1 && f < t.i1)) {
    t.v2 = t.v1; t.i2 = t.i1; t.v1 = z; t.i1 = f;
  } else if (z > t.v2 || (z == t.v2 && f < t.i2)) {
    t.v2 = z; t.i2 = f;
  }
}
__device__ __forceinline__ void t2_merge(Top2& t, float ov1, int oi1, float ov2,
                                         int oi2) {
  if (ov1 > t.v1 || (ov1 == t.v1 && oi1 < t.i1)) {
    const bool keep = (t.v1 > ov2) || (t.v1 == ov2 && t.i1 < oi2);
    t.v2 = keep ? t.v1 : ov2; t.i2 = keep ? t.i1 : oi2;
    t.v1 = ov1; t.i1 = oi1;
  } else if (ov1 > t.v2 || (ov1 == t.v2 && oi1 < t.i2)) {
    t.v2 = ov1; t.i2 = oi1;
  }
}

__device__ __forceinline__ uint2 pack_hi_trunc(float4 a) {
  uint2 r;
  r.x = (__float_as_uint(a.x) >> 16) | (__float_as_uint(a.y) & 0xffff0000u);
  r.y = (__float_as_uint(a.z) >> 16) | (__float_as_uint(a.w) & 0xffff0000u);
  return r;
}
__device__ __forceinline__ float4 resid_trunc(float4 a) {
  float4 r;
  r.x = a.x - __uint_as_float(__float_as_uint(a.x) & 0xffff0000u);
  r.y = a.y - __uint_as_float(__float_as_uint(a.y) & 0xffff0000u);
  r.z = a.z - __uint_as_float(__float_as_uint(a.z) & 0xffff0000u);
  r.w = a.w - __uint_as_float(__float_as_uint(a.w) & 0xffff0000u);
  return r;
}

// ============================================================================
// Operands pre-split to bf16 hi/lo in MFMA-blob order (fragment-exact 1KB
// blobs: blob[l][j] = elem(row/col=l&15, k=(l>>4)*8+j)). kc-major global
// layouts so the GEMM steps with one uniform stride:
//   xt: [kc(32)][mb(2048)][plane(2)][512 u16]   (kc stride 2 MB / 2097152 u16)
//   wt: [kc(32)][fb(40)]  [plane(2)][512 u16]   (kc stride 80 KB / 40960 u16)
// A is DMA'd to LDS (linear, conflict-free). B (L2-resident, 2.6 MB) is
// loaded DIRECTLY global->VGPR: the blob IS the fragment, 64 lanes x 16 B
// coalesced — no LDS staging, no B ds_reads.
// ============================================================================

// ---- W prep: blobs + fp32 W^T (for fast tie-recheck in k_select) ----
__global__ __launch_bounds__(256) void k_prep(const float* __restrict__ W,
                                              u16* __restrict__ wt,
                                              float* __restrict__ wtT) {
  const int tid = threadIdx.x;
  const int l = tid & 63;
  const int blob = blockIdx.x * 4 + (tid >> 6);   // 0..1279
  const int fb = blob >> 5, kc = blob & 31;
  const int f = fb * 16 + (l & 15);
  const int k0 = kc * 32 + (l >> 4) * 8;
  float v[8];
  ushort hh[8], ll[8];
#pragma unroll
  for (int j = 0; j < 8; ++j) {
    v[j] = W[(size_t)(k0 + j) * Fsz + f];
    hh[j] = f2bf(v[j]);
    ll[j] = f2bf(v[j] - bf2f(hh[j]));
  }
  uint4 qh, ql;
  qh.x = hh[0] | ((u32)hh[1] << 16); qh.y = hh[2] | ((u32)hh[3] << 16);
  qh.z = hh[4] | ((u32)hh[5] << 16); qh.w = hh[6] | ((u32)hh[7] << 16);
  ql.x = ll[0] | ((u32)ll[1] << 16); ql.y = ll[2] | ((u32)ll[3] << 16);
  ql.z = ll[4] | ((u32)ll[5] << 16); ql.w = ll[6] | ((u32)ll[7] << 16);
  const size_t b2 = (size_t)(kc * NFB + fb);
  *(uint4*)(wt + (b2 * 2 + 0) * 512 + l * 8) = qh;
  *(uint4*)(wt + (b2 * 2 + 1) * 512 + l * 8) = ql;
  float4 t0, t1;
  t0.x = v[0]; t0.y = v[1]; t0.z = v[2]; t0.w = v[3];
  t1.x = v[4]; t1.y = v[5]; t1.z = v[6]; t1.w = v[7];
  *(float4*)(wtT + (size_t)f * Esz + k0) = t0;
  *(float4*)(wtT + (size_t)f * Esz + k0 + 4) = t1;
}

// ---- x prep: trunc hi + trunc residual (bitwise-identical split) ----
__global__ __launch_bounds__(256) void k_prepx(const float* __restrict__ x,
                                               u16* __restrict__ xt) {
  const int tid = threadIdx.x;
  const int l = tid & 63;
  const int blob = blockIdx.x * 4 + (tid >> 6);   // 0..65535
  const int mb = blob >> 5, kc = blob & 31;
  const size_t row = (size_t)mb * 16 + (l & 15);
  const int k0 = kc * 32 + (l >> 4) * 8;
  const float4 a0 = *(const float4*)(x + row * Esz + k0);
  const float4 a1 = *(const float4*)(x + row * Esz + k0 + 4);
  const uint2 h0 = pack_hi_trunc(a0), h1 = pack_hi_trunc(a1);
  const uint2 l0 = pack_hi_trunc(resid_trunc(a0));
  const uint2 l1 = pack_hi_trunc(resid_trunc(a1));
  uint4 qh, ql;
  qh.x = h0.x; qh.y = h0.y; qh.z = h1.x; qh.w = h1.y;
  ql.x = l0.x; ql.y = l0.y; ql.z = l1.x; ql.w = l1.y;
  const size_t b2 = (size_t)kc * NMB + mb;
  *(uint4*)(xt + (b2 * 2 + 0) * 512 + l * 8) = qh;
  *(uint4*)(xt + (b2 * 2 + 1) * 512 + l * 8) = ql;
}

// ---- GEMM: BM=128 x BN=64. A: single 16 KB LDS buffer via DMA (R5's
// winning schedule). B: direct global->VGPR fragment loads (L2-resident),
// prefetched one K-step ahead into the same regs right after the MFMA
// cluster consumes them. setprio(1) around MFMAs (T5). ----
__global__ __launch_bounds__(256, 4) void k_gemm(
    const float* __restrict__ u, const float* __restrict__ bias,
    const u16* __restrict__ xt, const u16* __restrict__ wt,
    float4* __restrict__ partial) {
  __shared__ __align__(16) u16 sm[8192];  // 16 KB: A only, 16 x 1KB chunks

  const int tid = threadIdx.x;
  // XCD-chunked bijective swizzle: 2560 tiles = 8 XCDs x 320; n-tile fastest
  // within an XCD -> the 10 blocks sharing an xt m-panel hit one L2.
  const int bid = blockIdx.x;
  const int tile = (bid & 7) * 320 + (bid >> 3);
  const int mt = tile / 10, nt = tile - mt * 10;
  const int m0 = mt * BM;
  const int n0 = nt * 64;

  const int lane = tid & 63, w = tid >> 6;
  const int lrow = lane & 15, quad = lane >> 4;

  f32x4 acc[2][4];
#pragma unroll
  for (int i = 0; i < 2; ++i)
#pragma unroll
    for (int j = 0; j < 4; ++j) acc[i][j] = (f32x4){0.f, 0.f, 0.f, 0.f};

  // A: 16 chunks of 1 KB per K-step; wave w stages cc = w + 4*i (4 chunks,
  // wave-uniform dest as global_load_lds requires).
  // abase points at this block's m-panel for kc=0; +KSTEP_A per K-step.
  const size_t KSTEP_A = (size_t)NMB * 1024;  // u16 per kc
  const size_t KSTEP_B = (size_t)NFB * 1024;  // u16 per kc
  const u16* abase = xt + (size_t)(m0 >> 4) * 1024 + lane * 8;
  const u16* wbase = wt + (size_t)(n0 >> 4) * 1024 + lane * 8;

  auto stageA = [&](int kc) {
    const u16* s = abase + (size_t)kc * KSTEP_A;
#pragma unroll
    for (int i = 0; i < 4; ++i) {
      const int cc = w + 4 * i;
      load_lds16(s + cc * 512, sm + cc * 512);
    }
  };

  bf16x8 bh[4], bl[4];
  auto loadB = [&](int kc) {
    const u16* s = wbase + (size_t)kc * KSTEP_B;
#pragma unroll
    for (int ct = 0; ct < 4; ++ct) {
      bh[ct] = *(const bf16x8*)(s + ct * 1024);
      bl[ct] = *(const bf16x8*)(s + ct * 1024 + 512);
    }
  };

  stageA(0);
  loadB(0);

  for (int kc = 0; kc < NKC; ++kc) {
    __syncthreads();  // vmcnt(0): A(kc) DMA landed, B(kc) regs landed
    bf16x8 ah[2], al[2];
#pragma unroll
    for (int rt = 0; rt < 2; ++rt) {
      const int blk = w * 2 + rt;
      ah[rt] = *(const bf16x8*)(sm + (blk * 2 + 0) * 512 + lane * 8);
      al[rt] = *(const bf16x8*)(sm + (blk * 2 + 1) * 512 + lane * 8);
    }
    __syncthreads();  // all waves' A reads done -> LDS safe to overwrite
    if (kc + 1 < NKC) stageA(kc + 1);
    __builtin_amdgcn_sched_barrier(0);  // pin DMA issue before MFMA cluster
    __builtin_amdgcn_s_setprio(1);
#pragma unroll
    for (int ct = 0; ct < 4; ++ct)
#pragma unroll
      for (int rt = 0; rt < 2; ++rt) {
        acc[rt][ct] = __builtin_amdgcn_mfma_f32_16x16x32_bf16(al[rt], bh[ct], acc[rt][ct], 0, 0, 0);
        acc[rt][ct] = __builtin_amdgcn_mfma_f32_16x16x32_bf16(ah[rt], bl[ct], acc[rt][ct], 0, 0, 0);
        acc[rt][ct] = __builtin_amdgcn_mfma_f32_16x16x32_bf16(ah[rt], bh[ct], acc[rt][ct], 0, 0, 0);
      }
    __builtin_amdgcn_s_setprio(0);
    if (kc + 1 < NKC) loadB(kc + 1);  // WAR-safe: issued after MFMAs read regs
  }
  // no trailing barrier: epilogue does not touch LDS

  // ---- epilogue: z = h + bias + gumbel ; per-row top-2 over block's 64 cols
  const int pcol = nt;  // 64-col block id, 0..9
#pragma unroll
  for (int rt = 0; rt < 2; ++rt) {
#pragma unroll
    for (int rg = 0; rg < 4; ++rg) {
      const int row = w * 32 + rt * 16 + quad * 4 + rg;  // C/D row=quad*4+reg
      const size_t m = (size_t)(m0 + row);
      Top2 t; t.v1 = -3.4e38f; t.v2 = -3.4e38f; t.i1 = 1 << 30; t.i2 = 1 << 30;
#pragma unroll
      for (int ct = 0; ct < 4; ++ct) {
        const int f = n0 + ct * 16 + lrow;               // C/D col=lane&15
        const float z = acc[rt][ct][rg] + bias[f] + gumb_fast(u[m * 640 + f]);
        t2_feed(t, z, f);
      }
#pragma unroll
      for (int off = 1; off < 16; off <<= 1) {
        const float ov1 = __shfl_xor(t.v1, off, 16);
        const int oi1 = __shfl_xor(t.i1, off, 16);
        const float ov2 = __shfl_xor(t.v2, off, 16);
        const int oi2 = __shfl_xor(t.i2, off, 16);
        t2_merge(t, ov1, oi1, ov2, oi2);
      }
      if (lrow == 0) {
        float4 o;
        o.x = t.v1; o.y = __int_as_float(t.i1);
        o.z = t.v2; o.w = __int_as_float(t.i2);
        partial[m * 10 + pcol] = o;
      }
    }
  }
}

// ---- select (index only): merge partials, exact recheck near ties using
// fp32 W^T (contiguous rows; same fmaf order as before -> same result) ----
__global__ __launch_bounds__(256) void k_select(
    const float4* __restrict__ partial, const float* __restrict__ x,
    const float* __restrict__ wtT, const float* __restrict__ bias,
    const float* __restrict__ u, int2* __restrict__ idx_out,
    int* __restrict__ counts) {
  const int tid = threadIdx.x;
  const size_t m = (size_t)blockIdx.x * 256 + tid;
  int vsel[2];
#pragma unroll
  for (int g = 0; g < 2; ++g) {
    Top2 t; t.v1 = -3.4e38f; t.v2 = -3.4e38f; t.i1 = 1 << 30; t.i2 = 1 << 30;
#pragma unroll
    for (int p = 0; p < 5; ++p) {
      const float4 q = partial[m * 10 + g * 5 + p];
      t2_merge(t, q.x, __float_as_int(q.y), q.z, __float_as_int(q.w));
    }
    int i1 = t.i1;
    if (t.v1 - t.v2 < 1e-3f) {  // near tie: exact fp32 recheck of both
      const int i2 = t.i2;
      const float* xp = x + m * Esz;
      const float* w1 = wtT + (size_t)i1 * Esz;
      const float* w2 = wtT + (size_t)i2 * Esz;
      float h1 = 0.f, h2 = 0.f;
      for (int k = 0; k < Esz; k += 4) {
        const float4 xv = *(const float4*)(xp + k);
        const float4 a = *(const float4*)(w1 + k);
        const float4 b = *(const float4*)(w2 + k);
        h1 = fmaf(xv.x, a.x, h1); h1 = fmaf(xv.y, a.y, h1);
        h1 = fmaf(xv.z, a.z, h1); h1 = fmaf(xv.w, a.w, h1);
        h2 = fmaf(xv.x, b.x, h2); h2 = fmaf(xv.y, b.y, h2);
        h2 = fmaf(xv.z, b.z, h2); h2 = fmaf(xv.w, b.w, h2);
      }
      const float z1 = h1 + bias[i1] + gumb_precise(u[m * 640 + i1]);
      const float z2 = h2 + bias[i2] + gumb_precise(u[m * 640 + i2]);
      if (z2 > z1 || (z2 == z1 && i2 < i1)) i1 = i2;
    }
    const int v = i1 - g * Vsz;
    vsel[g] = v;
    const int b = (int)(m >> 11);  // N=2048
    atomicAdd(&counts[(b * Gsz + g) * Vsz + v], 1);
  }
  int2 r; r.x = vsel[0]; r.y = vsel[1];
  idx_out[m] = r;
}

// ---- gather: 4096 blocks x 8 rows, full-GPU output write ----
__global__ __launch_bounds__(256) void k_gather(const int2* __restrict__ idx,
                                                const float* __restrict__ cb,
                                                float* __restrict__ out) {
  const int tid = threadIdx.x;
  const size_t mbase = (size_t)blockIdx.x * 8;
  const int gq = tid >> 7, dq = tid & 127;
#pragma unroll
  for (int it = 0; it < 8; ++it) {
    const int2 p = idx[mbase + it];  // same addr all threads: broadcast
    const int v = gq ? p.y : p.x;
    const float4 cv =
        *(const float4*)(cb + ((size_t)(gq * Vsz + v)) * Dsz + dq * 4);
    *(float4*)(out + (mbase + it) * (size_t)(Gsz * Dsz) + tid * 4) = cv;
  }
}

// ============================================================================
// FALLBACK PATH — used only if ws_size is too small for the 134 MB xt buffer.
// ============================================================================

__global__ __launch_bounds__(256) void k_prep_fb(const float* __restrict__ W,
                                                 u16* __restrict__ wt_h,
                                                 u16* __restrict__ wt_l) {
  const int f = blockIdx.x;    // 0..639
  const int k0 = threadIdx.x * 4;
  float v[4];
#pragma unroll
  for (int i = 0; i < 4; ++i) v[i] = W[(size_t)(k0 + i) * Fsz + f];
  ushort4 hh, ll;
  hh.x = f2bf(v[0]); ll.x = f2bf(v[0] - bf2f(hh.x));
  hh.y = f2bf(v[1]); ll.y = f2bf(v[1] - bf2f(hh.y));
  hh.z = f2bf(v[2]); ll.z = f2bf(v[2] - bf2f(hh.z));
  hh.w = f2bf(v[3]); ll.w = f2bf(v[3] - bf2f(hh.w));
  *(ushort4*)(wt_h + (size_t)f * Esz + k0) = hh;
  *(ushort4*)(wt_l + (size_t)f * Esz + k0) = ll;
}

__global__ __launch_bounds__(256) void k_gemm_fb(
    const float* __restrict__ x, const float* __restrict__ u,
    const float* __restrict__ bias, const u16* __restrict__ wth,
    const u16* __restrict__ wtl, float4* __restrict__ partial) {
  __shared__ __align__(16) u16 sm[16384];  // 32 KB
  u16* xs_h = sm;            // 128x32
  u16* xs_l = sm + 4096;
  u16* bs_h = sm + 8192;     // 128x32 (local cols)
  u16* bs_l = sm + 12288;

  const int tid = threadIdx.x;
  const int n0 = blockIdx.x * BN;
  const int m0 = blockIdx.y * BM;
  const int lane = tid & 63, w = tid >> 6;
  const int wr = w >> 1, wc = w & 1;
  const int lrow = lane & 15, quad = lane >> 4;

  f32x4 acc[4][4];
#pragma unroll
  for (int i = 0; i < 4; ++i)
#pragma unroll
    for (int j = 0; j < 4; ++j) acc[i][j] = (f32x4){0.f, 0.f, 0.f, 0.f};

  for (int k0 = 0; k0 < Esz; k0 += BK) {
    float4 av[4];
#pragma unroll
    for (int s = 0; s < 4; ++s) {
      const int id = tid + 256 * s;
      const int row = id >> 3, kq = id & 7;
      av[s] = *(const float4*)(x + (size_t)(m0 + row) * Esz + k0 + kq * 4);
    }
    __syncthreads();
#pragma unroll
    for (int c = 0; c < 4; ++c) {
      const int chunk = w + 4 * c;
      const int plane = chunk >> 3, ch = chunk & 7;
      const u16* src = (plane ? wtl : wth) +
                       (size_t)(n0 + ch * 16 + (lane >> 2)) * Esz + k0 +
                       (lane & 3) * 8;
      u16* dst = (plane ? bs_l : bs_h) + ch * 512;
      load_lds16(src, dst);
    }
#pragma unroll
    for (int s = 0; s < 4; ++s) {
      const int id = tid + 256 * s;
      const int row = id >> 3, kq = id & 7;
      const u32 u0 = __float_as_uint(av[s].x), u1 = __float_as_uint(av[s].y);
      const u32 u2 = __float_as_uint(av[s].z), u3 = __float_as_uint(av[s].w);
      uint2 hh, ll;
      hh.x = (u0 >> 16) | (u1 & 0xffff0000u);
      hh.y = (u2 >> 16) | (u3 & 0xffff0000u);
      const float r0 = av[s].x - __uint_as_float(u0 & 0xffff0000u);
      const float r1 = av[s].y - __uint_as_float(u1 & 0xffff0000u);
      const float r2 = av[s].z - __uint_as_float(u2 & 0xffff0000u);
      const float r3 = av[s].w - __uint_as_float(u3 & 0xffff0000u);
      ll.x = (__float_as_uint(r0) >> 16) | (__float_as_uint(r1) & 0xffff0000u);
      ll.y = (__float_as_uint(r2) >> 16) | (__float_as_uint(r3) & 0xffff0000u);
      *(uint2*)(xs_h + row * 32 + kq * 4) = hh;
      *(uint2*)(xs_l + row * 32 + kq * 4) = ll;
    }
    __syncthreads();

    bf16x8 ah[4], al[4];
#pragma unroll
    for (int rt = 0; rt < 4; ++rt) {
      const int off = (wr * 64 + rt * 16 + lrow) * 32 + quad * 8;
      ah[rt] = *(const bf16x8*)(xs_h + off);
      al[rt] = *(const bf16x8*)(xs_l + off);
    }
#pragma unroll
    for (int ct = 0; ct < 4; ++ct) {
      const int off = (wc * 64 + ct * 16 + lrow) * 32 + quad * 8;
      const bf16x8 bh = *(const bf16x8*)(bs_h + off);
      const bf16x8 bl = *(const bf16x8*)(bs_l + off);
#pragma unroll
      for (int rt = 0; rt < 4; ++rt) {
        acc[rt][ct] = __builtin_amdgcn_mfma_f32_16x16x32_bf16(al[rt], bh, acc[rt][ct], 0, 0, 0);
        acc[rt][ct] = __builtin_amdgcn_mfma_f32_16x16x32_bf16(ah[rt], bl, acc[rt][ct], 0, 0, 0);
        acc[rt][ct] = __builtin_amdgcn_mfma_f32_16x16x32_bf16(ah[rt], bh, acc[rt][ct], 0, 0, 0);
      }
    }
  }

  const int pcol = blockIdx.x * 2 + wc;
#pragma unroll
  for (int rt = 0; rt < 4; ++rt) {
#pragma unroll
    for (int rg = 0; rg < 4; ++rg) {
      const int row = wr * 64 + rt * 16 + quad * 4 + rg;
      const size_t m = (size_t)(m0 + row);
      Top2 t; t.v1 = -3.4e38f; t.v2 = -3.4e38f; t.i1 = 1 << 30; t.i2 = 1 << 30;
#pragma unroll
      for (int ct = 0; ct < 4; ++ct) {
        const int f = n0 + wc * 64 + ct * 16 + lrow;
        const float z = acc[rt][ct][rg] + bias[f] + gumb_fast(u[m * 640 + f]);
        t2_feed(t, z, f);
      }
#pragma unroll
      for (int off = 1; off < 16; off <<= 1) {
        const float ov1 = __shfl_xor(t.v1, off, 16);
        const int oi1 = __shfl_xor(t.i1, off, 16);
        const float ov2 = __shfl_xor(t.v2, off, 16);
        const int oi2 = __shfl_xor(t.i2, off, 16);
        t2_merge(t, ov1, oi1, ov2, oi2);
      }
      if (lrow == 0) {
        float4 o;
        o.x = t.v1; o.y = __int_as_float(t.i1);
        o.z = t.v2; o.w = __int_as_float(t.i2);
        partial[m * 10 + pcol] = o;
      }
    }
  }
}

__global__ __launch_bounds__(256) void k_select_fb(
    const float4* __restrict__ partial, const float* __restrict__ x,
    const float* __restrict__ W, const float* __restrict__ bias,
    const float* __restrict__ u, const float* __restrict__ cb,
    float* __restrict__ out, int* __restrict__ counts) {
  __shared__ int idx_sh[256][2];
  const int tid = threadIdx.x;
  const size_t m = (size_t)blockIdx.x * 256 + tid;

#pragma unroll
  for (int g = 0; g < 2; ++g) {
    Top2 t; t.v1 = -3.4e38f; t.v2 = -3.4e38f; t.i1 = 1 << 30; t.i2 = 1 << 30;
#pragma unroll
    for (int p = 0; p < 5; ++p) {
      const float4 q = partial[m * 10 + g * 5 + p];
      t2_merge(t, q.x, __float_as_int(q.y), q.z, __float_as_int(q.w));
    }
    int i1 = t.i1;
    if (t.v1 - t.v2 < 1e-3f) {
      const int i2 = t.i2;
      const float* xp = x + m * Esz;
      float h1 = 0.f, h2 = 0.f;
      for (int k = 0; k < Esz; ++k) {
        const float xv = xp[k];
        h1 = fmaf(xv, W[(size_t)k * Fsz + i1], h1);
        h2 = fmaf(xv, W[(size_t)k * Fsz + i2], h2);
      }
      const float z1 = h1 + bias[i1] + gumb_precise(u[m * 640 + i1]);
      const float z2 = h2 + bias[i2] + gumb_precise(u[m * 640 + i2]);
      if (z2 > z1 || (z2 == z1 && i2 < i1)) i1 = i2;
    }
    const int v = i1 - g * Vsz;
    idx_sh[tid][g] = v;
    const int b = (int)(m >> 11);
    atomicAdd(&counts[(b * Gsz + g) * Vsz + v], 1);
  }
  __syncthreads();

  const size_t mbase = (size_t)blockIdx.x * 256;
  const int gq = tid >> 7, dq = tid & 127;
  for (int it = 0; it < 256; ++it) {
    const int v = idx_sh[it][gq];
    const float4 cv =
        *(const float4*)(cb + ((size_t)(gq * Vsz + v)) * Dsz + dq * 4);
    *(float4*)(out + (mbase + it) * (size_t)(Gsz * Dsz) + tid * 4) = cv;
  }
}

// ---- entropy over histogram ----
__global__ __launch_bounds__(64) void k_entropy(const int* __restrict__ counts,
                                                float* __restrict__ partial) {
  const int bg = blockIdx.x;
  const int lane = threadIdx.x;
  float c[5];
  float mx = -3.4e38f;
#pragma unroll
  for (int t = 0; t < 5; ++t) {
    c[t] = (float)counts[bg * Vsz + lane + 64 * t];
    mx = fmaxf(mx, c[t]);
  }
#pragma unroll
  for (int off = 32; off; off >>= 1) mx = fmaxf(mx, __shfl_xor(mx, off));
  float e[5];
  float s = 0.f;
#pragma unroll
  for (int t = 0; t < 5; ++t) {
    e[t] = expf(c[t] - mx);
    s += e[t];
  }
#pragma unroll
  for (int off = 32; off; off >>= 1) s += __shfl_xor(s, off);
  float ent = 0.f;
#pragma unroll
  for (int t = 0; t < 5; ++t) {
    const float p = e[t] / s;
    ent += p * logf(p + 1e-8f);
  }
#pragma unroll
  for (int off = 32; off; off >>= 1) ent += __shfl_xor(ent, off);
  if (lane == 0) partial[bg] = ent;
}

__global__ __launch_bounds__(64) void k_final(const float* __restrict__ partial,
                                              float* __restrict__ dst) {
  const int lane = threadIdx.x;
  float v = (lane < 32) ? partial[lane] : 0.f;
#pragma unroll
  for (int off = 32; off; off >>= 1) v += __shfl_xor(v, off);
  if (lane == 0) dst[0] = -v / (float)(Gsz * Vsz);
}

}  // namespace

extern "C" void kernel_launch(void* const* d_in, const int* in_sizes, int n_in,
                              void* d_out, int out_size, void* d_ws,
                              size_t ws_size, hipStream_t stream) {
  const float* x = (const float*)d_in[0];
  const float* u = (const float*)d_in[1];
  const float* W = (const float*)d_in[2];
  const float* bias = (const float*)d_in[3];
  const float* cb = (const float*)d_in[4];
  float* out = (float*)d_out;

  // ws layout (new path):
  // [0,40960) counts | [40960,41088) epart | [65536, +5242880) partials |
  // idx 262144 | wt 2621440 | wtT 2621440 | xt 134217728
  int* counts = (int*)d_ws;
  float* epart = (float*)((char*)d_ws + 40960);
  float4* partial = (float4*)((char*)d_ws + 65536);
  const size_t PART_END = 65536 + (size_t)Msz * 10 * 16;  // 5308416
  const size_t NEED_NEW =
      PART_END + 262144 + 2621440 + 2621440 + (size_t)Msz * Esz * 4;

  hipMemsetAsync(d_ws, 0, 40960, stream);

  if (ws_size >= NEED_NEW) {
    int2* idx = (int2*)((char*)d_ws + PART_END);
    u16* wt = (u16*)((char*)d_ws + PART_END + 262144);
    float* wtT = (float*)((char*)d_ws + PART_END + 262144 + 2621440);
    u16* xt = (u16*)((char*)d_ws + PART_END + 262144 + 2621440 + 2621440);
    k_prep<<<320, 256, 0, stream>>>(W, wt, wtT);
    k_prepx<<<16384, 256, 0, stream>>>(x, xt);
    k_gemm<<<(Msz / BM) * 10, 256, 0, stream>>>(u, bias, xt, wt, partial);
    k_select<<<Msz / 256, 256, 0, stream>>>(partial, x, wtT, bias, u, idx,
                                            counts);
    k_gather<<<Msz / 8, 256, 0, stream>>>(idx, cb, out);
  } else {
    u16* wth = (u16*)((char*)d_ws + PART_END);
    u16* wtl = wth + (size_t)Fsz * Esz;
    k_prep_fb<<<Fsz, 256, 0, stream>>>(W, wth, wtl);
    k_gemm_fb<<<dim3(Fsz / BN, Msz / BM), 256, 0, stream>>>(x, u, bias, wth,
                                                            wtl, partial);
    k_select_fb<<<Msz / 256, 256, 0, stream>>>(partial, x, W, bias, u, cb, out,
                                               counts);
  }
  k_entropy<<<Bsz * Gsz, 64, 0, stream>>>(counts, epart);
  k_final<<<1, 64, 0, stream>>>(epart, out + (size_t)Msz * Esz);
}

// Round 17
// 512.518 us; speedup vs baseline: 1.0728x; 1.0728x over previous
//
#include <hip/hip_runtime.h>

namespace {

constexpr int Bsz = 16, Nsz = 2048, Esz = 1024, Gsz = 2, Vsz = 320, Dsz = 512;
constexpr int Msz = Bsz * Nsz;   // 32768 rows
constexpr int Fsz = Gsz * Vsz;   // 640
constexpr int BM = 128, BN = 128, BK = 32;
constexpr int NKC = Esz / 32;    // 32 k-chunks
constexpr int NMB = Msz / 16;    // 2048 m-blobs
constexpr int NFB = Fsz / 16;    // 40 f-blobs

typedef __attribute__((ext_vector_type(8))) short bf16x8;
typedef __attribute__((ext_vector_type(4))) float f32x4;
typedef unsigned int u32;
typedef unsigned short u16;

__device__ __forceinline__ void load_lds16(const void* g, void* l) {
  __builtin_amdgcn_global_load_lds(
      (const __attribute__((address_space(1))) u32*)g,
      (__attribute__((address_space(3))) u32*)l, 16, 0, 0);
}

__device__ __forceinline__ ushort f2bf(float f) {
  union { float f; unsigned u; } v; v.f = f;
  unsigned r = (v.u + 0x7FFFu + ((v.u >> 16) & 1u)) >> 16;  // RNE
  return (ushort)r;
}
__device__ __forceinline__ float bf2f(ushort h) {
  union { unsigned u; float f; } v; v.u = ((unsigned)h) << 16;
  return v.f;
}

// precise gumbel (matches earlier rounds which scored absmax 0)
__device__ __forceinline__ float gumb_precise(float uu) {
  const float C0 = 1.0f - 2.0f * 1e-7f;
  float up = uu * C0;
  up = up + 1e-7f;
  return -logf(-logf(up));
}
// fast gumbel for candidate SELECTION only (abs err <~2e-5, threshold 1e-3)
__device__ __forceinline__ float gumb_fast(float uu) {
  const float C0 = 1.0f - 2.0f * 1e-7f;
  const float up = fmaf(uu, C0, 1e-7f);
  const float d = 1.0f - up;  // exact for up>=0.5 (Sterbenz)
  const float ypoly =
      d * fmaf(d, fmaf(d, fmaf(d, fmaf(d, 0.2f, 0.25f), 0.33333334f), 0.5f), 1.0f);
  const float yfast = -__logf(up);
  const float y = (up >= 0.84f) ? ypoly : yfast;
  return -__logf(y);
}

struct Top2 { float v1, v2; int i1, i2; };
__device__ __forceinline__ void t2_feed(Top2& t, float z, int f) {
  if (z > t.v1 || (z == t.v1 && f < t.i1)) {
    t.v2 = t.v1; t.i2 = t.i1; t.v1 = z; t.i1 = f;
  } else if (z > t.v2 || (z == t.v2 && f < t.i2)) {
    t.v2 = z; t.i2 = f;
  }
}
__device__ __forceinline__ void t2_merge(Top2& t, float ov1, int oi1, float ov2,
                                         int oi2) {
  if (ov1 > t.v1 || (ov1 == t.v1 && oi1 < t.i1)) {
    const bool keep = (t.v1 > ov2) || (t.v1 == ov2 && t.i1 < oi2);
    t.v2 = keep ? t.v1 : ov2; t.i2 = keep ? t.i1 : oi2;
    t.v1 = ov1; t.i1 = oi1;
  } else if (ov1 > t.v2 || (ov1 == t.v2 && oi1 < t.i2)) {
    t.v2 = ov1; t.i2 = oi1;
  }
}

__device__ __forceinline__ uint2 pack_hi_trunc(float4 a) {
  uint2 r;
  r.x = (__float_as_uint(a.x) >> 16) | (__float_as_uint(a.y) & 0xffff0000u);
  r.y = (__float_as_uint(a.z) >> 16) | (__float_as_uint(a.w) & 0xffff0000u);
  return r;
}
__device__ __forceinline__ float4 resid_trunc(float4 a) {
  float4 r;
  r.x = a.x - __uint_as_float(__float_as_uint(a.x) & 0xffff0000u);
  r.y = a.y - __uint_as_float(__float_as_uint(a.y) & 0xffff0000u);
  r.z = a.z - __uint_as_float(__float_as_uint(a.z) & 0xffff0000u);
  r.w = a.w - __uint_as_float(__float_as_uint(a.w) & 0xffff0000u);
  return r;
}

// ============================================================================
// Operands pre-split to bf16 hi/lo in MFMA-blob order (fragment-exact 1KB
// blobs: blob[l][j] = elem(row/col=l&15, k=(l>>4)*8+j)). kc-major global
// layouts so the GEMM steps with one uniform stride:
//   xt: [kc(32)][mb(2048)][plane(2)][512 u16]
//   wt: [kc(32)][fb(40)]  [plane(2)][512 u16]
// A (each wave reads ONLY its own 32 rows -> zero cross-wave reuse) is loaded
// DIRECTLY global->VGPR, double-buffered regs, prefetched 1 step ahead.
// B (read by all 4 waves -> reuse=4) is staged via global_load_lds into a
// 2 x 8KB LDS double buffer, staged 1 step ahead -> ONE barrier per K-step.
// ============================================================================

// ---- W prep: blobs + fp32 W^T (for fast tie-recheck in k_select) ----
__global__ __launch_bounds__(256) void k_prep(const float* __restrict__ W,
                                              u16* __restrict__ wt,
                                              float* __restrict__ wtT) {
  const int tid = threadIdx.x;
  const int l = tid & 63;
  const int blob = blockIdx.x * 4 + (tid >> 6);   // 0..1279
  const int fb = blob >> 5, kc = blob & 31;
  const int f = fb * 16 + (l & 15);
  const int k0 = kc * 32 + (l >> 4) * 8;
  float v[8];
  ushort hh[8], ll[8];
#pragma unroll
  for (int j = 0; j < 8; ++j) {
    v[j] = W[(size_t)(k0 + j) * Fsz + f];
    hh[j] = f2bf(v[j]);
    ll[j] = f2bf(v[j] - bf2f(hh[j]));
  }
  uint4 qh, ql;
  qh.x = hh[0] | ((u32)hh[1] << 16); qh.y = hh[2] | ((u32)hh[3] << 16);
  qh.z = hh[4] | ((u32)hh[5] << 16); qh.w = hh[6] | ((u32)hh[7] << 16);
  ql.x = ll[0] | ((u32)ll[1] << 16); ql.y = ll[2] | ((u32)ll[3] << 16);
  ql.z = ll[4] | ((u32)ll[5] << 16); ql.w = ll[6] | ((u32)ll[7] << 16);
  const size_t b2 = (size_t)(kc * NFB + fb);
  *(uint4*)(wt + (b2 * 2 + 0) * 512 + l * 8) = qh;
  *(uint4*)(wt + (b2 * 2 + 1) * 512 + l * 8) = ql;
  float4 t0, t1;
  t0.x = v[0]; t0.y = v[1]; t0.z = v[2]; t0.w = v[3];
  t1.x = v[4]; t1.y = v[5]; t1.z = v[6]; t1.w = v[7];
  *(float4*)(wtT + (size_t)f * Esz + k0) = t0;
  *(float4*)(wtT + (size_t)f * Esz + k0 + 4) = t1;
}

// ---- x prep: trunc hi + trunc residual (bitwise-identical split) ----
__global__ __launch_bounds__(256) void k_prepx(const float* __restrict__ x,
                                               u16* __restrict__ xt) {
  const int tid = threadIdx.x;
  const int l = tid & 63;
  const int blob = blockIdx.x * 4 + (tid >> 6);   // 0..65535
  const int mb = blob >> 5, kc = blob & 31;
  const size_t row = (size_t)mb * 16 + (l & 15);
  const int k0 = kc * 32 + (l >> 4) * 8;
  const float4 a0 = *(const float4*)(x + row * Esz + k0);
  const float4 a1 = *(const float4*)(x + row * Esz + k0 + 4);
  const uint2 h0 = pack_hi_trunc(a0), h1 = pack_hi_trunc(a1);
  const uint2 l0 = pack_hi_trunc(resid_trunc(a0));
  const uint2 l1 = pack_hi_trunc(resid_trunc(a1));
  uint4 qh, ql;
  qh.x = h0.x; qh.y = h0.y; qh.z = h1.x; qh.w = h1.y;
  ql.x = l0.x; ql.y = l0.y; ql.z = l1.x; ql.w = l1.y;
  const size_t b2 = (size_t)kc * NMB + mb;
  *(uint4*)(xt + (b2 * 2 + 0) * 512 + l * 8) = qh;
  *(uint4*)(xt + (b2 * 2 + 1) * 512 + l * 8) = ql;
}

// ---- GEMM: BM=128 x BN=64. A: direct global->VGPR, reg-dbuf, 1-step
// prefetch. B: 2x8KB LDS dbuf via DMA, 1-step prefetch. ONE barrier/K-step:
// top barrier drains in-flight stage+prefetch AND proves the other B buffer's
// readers finished (they ran before the barrier). setprio around MFMAs. ----
__global__ __launch_bounds__(256, 4) void k_gemm(
    const float* __restrict__ u, const float* __restrict__ bias,
    const u16* __restrict__ xt, const u16* __restrict__ wt,
    float4* __restrict__ partial) {
  __shared__ __align__(16) u16 sm[8192];  // 16 KB: B double buffer, 2 x 8 chunks

  const int tid = threadIdx.x;
  // XCD-chunked bijective swizzle: 2560 tiles = 8 XCDs x 320; n-tile fastest
  // within an XCD -> the 10 blocks sharing an xt m-panel hit one L2.
  const int bid = blockIdx.x;
  const int tile = (bid & 7) * 320 + (bid >> 3);
  const int mt = tile / 10, nt = tile - mt * 10;
  const int m0 = mt * BM;
  const int n0 = nt * 64;

  const int lane = tid & 63, w = tid >> 6;
  const int lrow = lane & 15, quad = lane >> 4;

  f32x4 acc[2][4];
#pragma unroll
  for (int i = 0; i < 2; ++i)
#pragma unroll
    for (int j = 0; j < 4; ++j) acc[i][j] = (f32x4){0.f, 0.f, 0.f, 0.f};

  const size_t KSTEP_A = (size_t)NMB * 1024;  // u16 per kc
  const size_t KSTEP_B = (size_t)NFB * 1024;  // u16 per kc
  // A: wave w owns m-blobs (m0>>4)+w*2 and +w*2+1 (its 32 rows).
  const u16* abase = xt + (size_t)((m0 >> 4) + w * 2) * 1024 + lane * 8;
  // B: block's 4 f-blobs are contiguous: fb0*1024 + cc*512, cc in [0,8).
  const u16* wbase = wt + (size_t)(n0 >> 4) * 1024 + lane * 8;

  // stage B(kc) into LDS buffer buf (8 chunks of 1KB; 2 per wave, uniform dst)
  auto stageB = [&](int kc, int buf) {
    const u16* s = wbase + (size_t)kc * KSTEP_B;
#pragma unroll
    for (int i = 0; i < 2; ++i) {
      const int cc = w + 4 * i;
      load_lds16(s + cc * 512, sm + buf * 4096 + cc * 512);
    }
  };

  // A register sets (named, static indexing — no runtime-indexed reg arrays)
  bf16x8 a0h0, a0h1, a0l0, a0l1;  // parity-0 set
  bf16x8 a1h0, a1h1, a1l0, a1l1;  // parity-1 set

#define PREF_A0(kc)                                            \
  {                                                            \
    const u16* s_ = abase + (size_t)(kc) * KSTEP_A;            \
    a0h0 = *(const bf16x8*)(s_);                               \
    a0l0 = *(const bf16x8*)(s_ + 512);                         \
    a0h1 = *(const bf16x8*)(s_ + 1024);                        \
    a0l1 = *(const bf16x8*)(s_ + 1536);                        \
  }
#define PREF_A1(kc)                                            \
  {                                                            \
    const u16* s_ = abase + (size_t)(kc) * KSTEP_A;            \
    a1h0 = *(const bf16x8*)(s_);                               \
    a1l0 = *(const bf16x8*)(s_ + 512);                         \
    a1h1 = *(const bf16x8*)(s_ + 1024);                        \
    a1l1 = *(const bf16x8*)(s_ + 1536);                        \
  }

  bf16x8 bh[4], bl[4];
  auto readB = [&](int buf) {
    const u16* base = sm + buf * 4096 + lane * 8;
#pragma unroll
    for (int ct = 0; ct < 4; ++ct) {
      bh[ct] = *(const bf16x8*)(base + ct * 1024);
      bl[ct] = *(const bf16x8*)(base + ct * 1024 + 512);
    }
  };

#define MFMA_CLUSTER(AH0, AL0, AH1, AL1)                                       \
  __builtin_amdgcn_s_setprio(1);                                               \
  _Pragma("unroll")                                                            \
  for (int ct = 0; ct < 4; ++ct) {                                             \
    acc[0][ct] = __builtin_amdgcn_mfma_f32_16x16x32_bf16(AL0, bh[ct], acc[0][ct], 0, 0, 0); \
    acc[0][ct] = __builtin_amdgcn_mfma_f32_16x16x32_bf16(AH0, bl[ct], acc[0][ct], 0, 0, 0); \
    acc[0][ct] = __builtin_amdgcn_mfma_f32_16x16x32_bf16(AH0, bh[ct], acc[0][ct], 0, 0, 0); \
    acc[1][ct] = __builtin_amdgcn_mfma_f32_16x16x32_bf16(AL1, bh[ct], acc[1][ct], 0, 0, 0); \
    acc[1][ct] = __builtin_amdgcn_mfma_f32_16x16x32_bf16(AH1, bl[ct], acc[1][ct], 0, 0, 0); \
    acc[1][ct] = __builtin_amdgcn_mfma_f32_16x16x32_bf16(AH1, bh[ct], acc[1][ct], 0, 0, 0); \
  }                                                                            \
  __builtin_amdgcn_s_setprio(0);

  // prologue: kc=0 in flight
  PREF_A0(0);
  stageB(0, 0);

  for (int it = 0; it < NKC / 2; ++it) {
    const int kc = it * 2;
    // ---- even sub-step: consumes A0 set + B buf0 ----
    __syncthreads();  // drains stage(kc->buf0) + prefA(kc->A0); buf1 readers done
    stageB(kc + 1, 1);          // kc+1 <= 31 always (kc <= 30)
    PREF_A1(kc + 1);
    __builtin_amdgcn_sched_barrier(0);  // pin issues before reads/MFMAs
    readB(0);
    MFMA_CLUSTER(a0h0, a0l0, a0h1, a0l1);
    // ---- odd sub-step: consumes A1 set + B buf1 ----
    __syncthreads();  // drains stage(kc+1->buf1) + prefA(kc+1); buf0 readers done
    if (kc + 2 < NKC) {
      stageB(kc + 2, 0);
      PREF_A0(kc + 2);
    }
    __builtin_amdgcn_sched_barrier(0);
    readB(1);
    MFMA_CLUSTER(a1h0, a1l0, a1h1, a1l1);
  }
#undef PREF_A0
#undef PREF_A1
#undef MFMA_CLUSTER
  // no trailing barrier: epilogue does not touch LDS

  // ---- epilogue: z = h + bias + gumbel ; per-row top-2 over block's 64 cols
  const int pcol = nt;  // 64-col block id, 0..9
#pragma unroll
  for (int rt = 0; rt < 2; ++rt) {
#pragma unroll
    for (int rg = 0; rg < 4; ++rg) {
      const int row = w * 32 + rt * 16 + quad * 4 + rg;  // C/D row=quad*4+reg
      const size_t m = (size_t)(m0 + row);
      Top2 t; t.v1 = -3.4e38f; t.v2 = -3.4e38f; t.i1 = 1 << 30; t.i2 = 1 << 30;
#pragma unroll
      for (int ct = 0; ct < 4; ++ct) {
        const int f = n0 + ct * 16 + lrow;               // C/D col=lane&15
        const float z = acc[rt][ct][rg] + bias[f] + gumb_fast(u[m * 640 + f]);
        t2_feed(t, z, f);
      }
#pragma unroll
      for (int off = 1; off < 16; off <<= 1) {
        const float ov1 = __shfl_xor(t.v1, off, 16);
        const int oi1 = __shfl_xor(t.i1, off, 16);
        const float ov2 = __shfl_xor(t.v2, off, 16);
        const int oi2 = __shfl_xor(t.i2, off, 16);
        t2_merge(t, ov1, oi1, ov2, oi2);
      }
      if (lrow == 0) {
        float4 o;
        o.x = t.v1; o.y = __int_as_float(t.i1);
        o.z = t.v2; o.w = __int_as_float(t.i2);
        partial[m * 10 + pcol] = o;
      }
    }
  }
}

// ---- select (index only): merge partials, exact recheck near ties using
// fp32 W^T (contiguous rows; same fmaf order as before -> same result) ----
__global__ __launch_bounds__(256) void k_select(
    const float4* __restrict__ partial, const float* __restrict__ x,
    const float* __restrict__ wtT, const float* __restrict__ bias,
    const float* __restrict__ u, int2* __restrict__ idx_out,
    int* __restrict__ counts) {
  const int tid = threadIdx.x;
  const size_t m = (size_t)blockIdx.x * 256 + tid;
  int vsel[2];
#pragma unroll
  for (int g = 0; g < 2; ++g) {
    Top2 t; t.v1 = -3.4e38f; t.v2 = -3.4e38f; t.i1 = 1 << 30; t.i2 = 1 << 30;
#pragma unroll
    for (int p = 0; p < 5; ++p) {
      const float4 q = partial[m * 10 + g * 5 + p];
      t2_merge(t, q.x, __float_as_int(q.y), q.z, __float_as_int(q.w));
    }
    int i1 = t.i1;
    if (t.v1 - t.v2 < 1e-3f) {  // near tie: exact fp32 recheck of both
      const int i2 = t.i2;
      const float* xp = x + m * Esz;
      const float* w1 = wtT + (size_t)i1 * Esz;
      const float* w2 = wtT + (size_t)i2 * Esz;
      float h1 = 0.f, h2 = 0.f;
      for (int k = 0; k < Esz; k += 4) {
        const float4 xv = *(const float4*)(xp + k);
        const float4 a = *(const float4*)(w1 + k);
        const float4 b = *(const float4*)(w2 + k);
        h1 = fmaf(xv.x, a.x, h1); h1 = fmaf(xv.y, a.y, h1);
        h1 = fmaf(xv.z, a.z, h1); h1 = fmaf(xv.w, a.w, h1);
        h2 = fmaf(xv.x, b.x, h2); h2 = fmaf(xv.y, b.y, h2);
        h2 = fmaf(xv.z, b.z, h2); h2 = fmaf(xv.w, b.w, h2);
      }
      const float z1 = h1 + bias[i1] + gumb_precise(u[m * 640 + i1]);
      const float z2 = h2 + bias[i2] + gumb_precise(u[m * 640 + i2]);
      if (z2 > z1 || (z2 == z1 && i2 < i1)) i1 = i2;
    }
    const int v = i1 - g * Vsz;
    vsel[g] = v;
    const int b = (int)(m >> 11);  // N=2048
    atomicAdd(&counts[(b * Gsz + g) * Vsz + v], 1);
  }
  int2 r; r.x = vsel[0]; r.y = vsel[1];
  idx_out[m] = r;
}

// ---- gather: 4096 blocks x 8 rows, full-GPU output write ----
__global__ __launch_bounds__(256) void k_gather(const int2* __restrict__ idx,
                                                const float* __restrict__ cb,
                                                float* __restrict__ out) {
  const int tid = threadIdx.x;
  const size_t mbase = (size_t)blockIdx.x * 8;
  const int gq = tid >> 7, dq = tid & 127;
#pragma unroll
  for (int it = 0; it < 8; ++it) {
    const int2 p = idx[mbase + it];  // same addr all threads: broadcast
    const int v = gq ? p.y : p.x;
    const float4 cv =
        *(const float4*)(cb + ((size_t)(gq * Vsz + v)) * Dsz + dq * 4);
    *(float4*)(out + (mbase + it) * (size_t)(Gsz * Dsz) + tid * 4) = cv;
  }
}

// ============================================================================
// FALLBACK PATH — used only if ws_size is too small for the 134 MB xt buffer.
// ============================================================================

__global__ __launch_bounds__(256) void k_prep_fb(const float* __restrict__ W,
                                                 u16* __restrict__ wt_h,
                                                 u16* __restrict__ wt_l) {
  const int f = blockIdx.x;    // 0..639
  const int k0 = threadIdx.x * 4;
  float v[4];
#pragma unroll
  for (int i = 0; i < 4; ++i) v[i] = W[(size_t)(k0 + i) * Fsz + f];
  ushort4 hh, ll;
  hh.x = f2bf(v[0]); ll.x = f2bf(v[0] - bf2f(hh.x));
  hh.y = f2bf(v[1]); ll.y = f2bf(v[1] - bf2f(hh.y));
  hh.z = f2bf(v[2]); ll.z = f2bf(v[2] - bf2f(hh.z));
  hh.w = f2bf(v[3]); ll.w = f2bf(v[3] - bf2f(hh.w));
  *(ushort4*)(wt_h + (size_t)f * Esz + k0) = hh;
  *(ushort4*)(wt_l + (size_t)f * Esz + k0) = ll;
}

__global__ __launch_bounds__(256) void k_gemm_fb(
    const float* __restrict__ x, const float* __restrict__ u,
    const float* __restrict__ bias, const u16* __restrict__ wth,
    const u16* __restrict__ wtl, float4* __restrict__ partial) {
  __shared__ __align__(16) u16 sm[16384];  // 32 KB
  u16* xs_h = sm;            // 128x32
  u16* xs_l = sm + 4096;
  u16* bs_h = sm + 8192;     // 128x32 (local cols)
  u16* bs_l = sm + 12288;

  const int tid = threadIdx.x;
  const int n0 = blockIdx.x * BN;
  const int m0 = blockIdx.y * BM;
  const int lane = tid & 63, w = tid >> 6;
  const int wr = w >> 1, wc = w & 1;
  const int lrow = lane & 15, quad = lane >> 4;

  f32x4 acc[4][4];
#pragma unroll
  for (int i = 0; i < 4; ++i)
#pragma unroll
    for (int j = 0; j < 4; ++j) acc[i][j] = (f32x4){0.f, 0.f, 0.f, 0.f};

  for (int k0 = 0; k0 < Esz; k0 += BK) {
    float4 av[4];
#pragma unroll
    for (int s = 0; s < 4; ++s) {
      const int id = tid + 256 * s;
      const int row = id >> 3, kq = id & 7;
      av[s] = *(const float4*)(x + (size_t)(m0 + row) * Esz + k0 + kq * 4);
    }
    __syncthreads();
#pragma unroll
    for (int c = 0; c < 4; ++c) {
      const int chunk = w + 4 * c;
      const int plane = chunk >> 3, ch = chunk & 7;
      const u16* src = (plane ? wtl : wth) +
                       (size_t)(n0 + ch * 16 + (lane >> 2)) * Esz + k0 +
                       (lane & 3) * 8;
      u16* dst = (plane ? bs_l : bs_h) + ch * 512;
      load_lds16(src, dst);
    }
#pragma unroll
    for (int s = 0; s < 4; ++s) {
      const int id = tid + 256 * s;
      const int row = id >> 3, kq = id & 7;
      const u32 u0 = __float_as_uint(av[s].x), u1 = __float_as_uint(av[s].y);
      const u32 u2 = __float_as_uint(av[s].z), u3 = __float_as_uint(av[s].w);
      uint2 hh, ll;
      hh.x = (u0 >> 16) | (u1 & 0xffff0000u);
      hh.y = (u2 >> 16) | (u3 & 0xffff0000u);
      const float r0 = av[s].x - __uint_as_float(u0 & 0xffff0000u);
      const float r1 = av[s].y - __uint_as_float(u1 & 0xffff0000u);
      const float r2 = av[s].z - __uint_as_float(u2 & 0xffff0000u);
      const float r3 = av[s].w - __uint_as_float(u3 & 0xffff0000u);
      ll.x = (__float_as_uint(r0) >> 16) | (__float_as_uint(r1) & 0xffff0000u);
      ll.y = (__float_as_uint(r2) >> 16) | (__float_as_uint(r3) & 0xffff0000u);
      *(uint2*)(xs_h + row * 32 + kq * 4) = hh;
      *(uint2*)(xs_l + row * 32 + kq * 4) = ll;
    }
    __syncthreads();

    bf16x8 ah[4], al[4];
#pragma unroll
    for (int rt = 0; rt < 4; ++rt) {
      const int off = (wr * 64 + rt * 16 + lrow) * 32 + quad * 8;
      ah[rt] = *(const bf16x8*)(xs_h + off);
      al[rt] = *(const bf16x8*)(xs_l + off);
    }
#pragma unroll
    for (int ct = 0; ct < 4; ++ct) {
      const int off = (wc * 64 + ct * 16 + lrow) * 32 + quad * 8;
      const bf16x8 bh = *(const bf16x8*)(bs_h + off);
      const bf16x8 bl = *(const bf16x8*)(bs_l + off);
#pragma unroll
      for (int rt = 0; rt < 4; ++rt) {
        acc[rt][ct] = __builtin_amdgcn_mfma_f32_16x16x32_bf16(al[rt], bh, acc[rt][ct], 0, 0, 0);
        acc[rt][ct] = __builtin_amdgcn_mfma_f32_16x16x32_bf16(ah[rt], bl, acc[rt][ct], 0, 0, 0);
        acc[rt][ct] = __builtin_amdgcn_mfma_f32_16x16x32_bf16(ah[rt], bh, acc[rt][ct], 0, 0, 0);
      }
    }
  }

  const int pcol = blockIdx.x * 2 + wc;
#pragma unroll
  for (int rt = 0; rt < 4; ++rt) {
#pragma unroll
    for (int rg = 0; rg < 4; ++rg) {
      const int row = wr * 64 + rt * 16 + quad * 4 + rg;
      const size_t m = (size_t)(m0 + row);
      Top2 t; t.v1 = -3.4e38f; t.v2 = -3.4e38f; t.i1 = 1 << 30; t.i2 = 1 << 30;
#pragma unroll
      for (int ct = 0; ct < 4; ++ct) {
        const int f = n0 + wc * 64 + ct * 16 + lrow;
        const float z = acc[rt][ct][rg] + bias[f] + gumb_fast(u[m * 640 + f]);
        t2_feed(t, z, f);
      }
#pragma unroll
      for (int off = 1; off < 16; off <<= 1) {
        const float ov1 = __shfl_xor(t.v1, off, 16);
        const int oi1 = __shfl_xor(t.i1, off, 16);
        const float ov2 = __shfl_xor(t.v2, off, 16);
        const int oi2 = __shfl_xor(t.i2, off, 16);
        t2_merge(t, ov1, oi1, ov2, oi2);
      }
      if (lrow == 0) {
        float4 o;
        o.x = t.v1; o.y = __int_as_float(t.i1);
        o.z = t.v2; o.w = __int_as_float(t.i2);
        partial[m * 10 + pcol] = o;
      }
    }
  }
}

__global__ __launch_bounds__(256) void k_select_fb(
    const float4* __restrict__ partial, const float* __restrict__ x,
    const float* __restrict__ W, const float* __restrict__ bias,
    const float* __restrict__ u, const float* __restrict__ cb,
    float* __restrict__ out, int* __restrict__ counts) {
  __shared__ int idx_sh[256][2];
  const int tid = threadIdx.x;
  const size_t m = (size_t)blockIdx.x * 256 + tid;

#pragma unroll
  for (int g = 0; g < 2; ++g) {
    Top2 t; t.v1 = -3.4e38f; t.v2 = -3.4e38f; t.i1 = 1 << 30; t.i2 = 1 << 30;
#pragma unroll
    for (int p = 0; p < 5; ++p) {
      const float4 q = partial[m * 10 + g * 5 + p];
      t2_merge(t, q.x, __float_as_int(q.y), q.z, __float_as_int(q.w));
    }
    int i1 = t.i1;
    if (t.v1 - t.v2 < 1e-3f) {
      const int i2 = t.i2;
      const float* xp = x + m * Esz;
      float h1 = 0.f, h2 = 0.f;
      for (int k = 0; k < Esz; ++k) {
        const float xv = xp[k];
        h1 = fmaf(xv, W[(size_t)k * Fsz + i1], h1);
        h2 = fmaf(xv, W[(size_t)k * Fsz + i2], h2);
      }
      const float z1 = h1 + bias[i1] + gumb_precise(u[m * 640 + i1]);
      const float z2 = h2 + bias[i2] + gumb_precise(u[m * 640 + i2]);
      if (z2 > z1 || (z2 == z1 && i2 < i1)) i1 = i2;
    }
    const int v = i1 - g * Vsz;
    idx_sh[tid][g] = v;
    const int b = (int)(m >> 11);
    atomicAdd(&counts[(b * Gsz + g) * Vsz + v], 1);
  }
  __syncthreads();

  const size_t mbase = (size_t)blockIdx.x * 256;
  const int gq = tid >> 7, dq = tid & 127;
  for (int it = 0; it < 256; ++it) {
    const int v = idx_sh[it][gq];
    const float4 cv =
        *(const float4*)(cb + ((size_t)(gq * Vsz + v)) * Dsz + dq * 4);
    *(float4*)(out + (mbase + it) * (size_t)(Gsz * Dsz) + tid * 4) = cv;
  }
}

// ---- entropy over histogram ----
__global__ __launch_bounds__(64) void k_entropy(const int* __restrict__ counts,
                                                float* __restrict__ partial) {
  const int bg = blockIdx.x;
  const int lane = threadIdx.x;
  float c[5];
  float mx = -3.4e38f;
#pragma unroll
  for (int t = 0; t < 5; ++t) {
    c[t] = (float)counts[bg * Vsz + lane + 64 * t];
    mx = fmaxf(mx, c[t]);
  }
#pragma unroll
  for (int off = 32; off; off >>= 1) mx = fmaxf(mx, __shfl_xor(mx, off));
  float e[5];
  float s = 0.f;
#pragma unroll
  for (int t = 0; t < 5; ++t) {
    e[t] = expf(c[t] - mx);
    s += e[t];
  }
#pragma unroll
  for (int off = 32; off; off >>= 1) s += __shfl_xor(s, off);
  float ent = 0.f;
#pragma unroll
  for (int t = 0; t < 5; ++t) {
    const float p = e[t] / s;
    ent += p * logf(p + 1e-8f);
  }
#pragma unroll
  for (int off = 32; off; off >>= 1) ent += __shfl_xor(ent, off);
  if (lane == 0) partial[bg] = ent;
}

__global__ __launch_bounds__(64) void k_final(const float* __restrict__ partial,
                                              float* __restrict__ dst) {
  const int lane = threadIdx.x;
  float v = (lane < 32) ? partial[lane] : 0.f;
#pragma unroll
  for (int off = 32; off; off >>= 1) v += __shfl_xor(v, off);
  if (lane == 0) dst[0] = -v / (float)(Gsz * Vsz);
}

}  // namespace

extern "C" void kernel_launch(void* const* d_in, const int* in_sizes, int n_in,
                              void* d_out, int out_size, void* d_ws,
                              size_t ws_size, hipStream_t stream) {
  const float* x = (const float*)d_in[0];
  const float* u = (const float*)d_in[1];
  const float* W = (const float*)d_in[2];
  const float* bias = (const float*)d_in[3];
  const float* cb = (const float*)d_in[4];
  float* out = (float*)d_out;

  // ws layout (new path):
  // [0,40960) counts | [40960,41088) epart | [65536, +5242880) partials |
  // idx 262144 | wt 2621440 | wtT 2621440 | xt 134217728
  int* counts = (int*)d_ws;
  float* epart = (float*)((char*)d_ws + 40960);
  float4* partial = (float4*)((char*)d_ws + 65536);
  const size_t PART_END = 65536 + (size_t)Msz * 10 * 16;  // 5308416
  const size_t NEED_NEW =
      PART_END + 262144 + 2621440 + 2621440 + (size_t)Msz * Esz * 4;

  hipMemsetAsync(d_ws, 0, 40960, stream);

  if (ws_size >= NEED_NEW) {
    int2* idx = (int2*)((char*)d_ws + PART_END);
    u16* wt = (u16*)((char*)d_ws + PART_END + 262144);
    float* wtT = (float*)((char*)d_ws + PART_END + 262144 + 2621440);
    u16* xt = (u16*)((char*)d_ws + PART_END + 262144 + 2621440 + 2621440);
    k_prep<<<320, 256, 0, stream>>>(W, wt, wtT);
    k_prepx<<<16384, 256, 0, stream>>>(x, xt);
    k_gemm<<<(Msz / BM) * 10, 256, 0, stream>>>(u, bias, xt, wt, partial);
    k_select<<<Msz / 256, 256, 0, stream>>>(partial, x, wtT, bias, u, idx,
                                            counts);
    k_gather<<<Msz / 8, 256, 0, stream>>>(idx, cb, out);
  } else {
    u16* wth = (u16*)((char*)d_ws + PART_END);
    u16* wtl = wth + (size_t)Fsz * Esz;
    k_prep_fb<<<Fsz, 256, 0, stream>>>(W, wth, wtl);
    k_gemm_fb<<<dim3(Fsz / BN, Msz / BM), 256, 0, stream>>>(x, u, bias, wth,
                                                            wtl, partial);
    k_select_fb<<<Msz / 256, 256, 0, stream>>>(partial, x, W, bias, u, cb, out,
                                               counts);
  }
  k_entropy<<<Bsz * Gsz, 64, 0, stream>>>(counts, epart);
  k_final<<<1, 64, 0, stream>>>(epart, out + (size_t)Msz * Esz);
}